// Round 1
// baseline (100.013 us; speedup 1.0000x reference)
//
#include <hip/hip_runtime.h>
#include <hip/hip_bf16.h>

// ComputeEmbeddings: out[b,s,d] = embed_weight[inputs[b,s], d] + PE[s,d]
//   B=32, S=5000, D=512, VOCAB=32000, fp32.
// PE[s,2i]   = sin(s / 10000^(2i/D))
// PE[s,2i+1] = cos(s / 10000^(2i/D))
//
// Strategy: one thread per (s, d-quad). Compute the 4 PE values once per
// thread (PE is batch-independent), then loop over the 32 batches doing a
// float4 gather + add + float4 store. Token is wave-uniform (s uniform per
// wave, d4 = lane*4) -> gather and store are fully coalesced 16B/lane.

#define EMB_B 32
#define EMB_S 5000
#define EMB_D 512
#define EMB_DV (EMB_D / 4)   // 128 float4 per row

__global__ __launch_bounds__(256) void ComputeEmbeddings_50440095924269_kernel(
    const int* __restrict__ inputs,      // [B, S]
    const float* __restrict__ weight,    // [VOCAB, D]
    float* __restrict__ out)             // [B, S, D]
{
    const int tid = blockIdx.x * blockDim.x + threadIdx.x;  // 0 .. S*EMB_DV-1
    const int dvec = tid & (EMB_DV - 1);     // 0..127  (d4 = dvec*4)
    const int s    = tid >> 7;               // 0..4999
    if (s >= EMB_S) return;

    // --- positional encoding for dims d4 .. d4+3 (pairs i0, i0+1) ---
    const int d4 = dvec << 2;
    const float LOG2_10000 = 13.287712379549449f;  // log2(10000)
    const float i0 = (float)(d4 >> 1);
    // inv_freq(i) = 10000^(-2i/D) = exp2(-(2i/D) * log2(10000))
    const float f0 = exp2f(-(2.0f * i0 / (float)EMB_D) * LOG2_10000);
    const float f1 = exp2f(-(2.0f * (i0 + 1.0f) / (float)EMB_D) * LOG2_10000);
    const float a0 = (float)s * f0;
    const float a1 = (float)s * f1;
    float4 pe;
    pe.x = sinf(a0); pe.y = cosf(a0);
    pe.z = sinf(a1); pe.w = cosf(a1);

    const float4* __restrict__ w4 = reinterpret_cast<const float4*>(weight);
    float4* __restrict__ o4 = reinterpret_cast<float4*>(out);
    const int row_off = s * EMB_DV + dvec;

    #pragma unroll 8
    for (int b = 0; b < EMB_B; ++b) {
        const int token = inputs[b * EMB_S + s];          // wave-uniform
        const float4 e = w4[(size_t)token * EMB_DV + dvec];
        float4 r;
        r.x = e.x + pe.x;
        r.y = e.y + pe.y;
        r.z = e.z + pe.z;
        r.w = e.w + pe.w;
        o4[(size_t)b * (EMB_S * EMB_DV) + row_off] = r;
    }
}

extern "C" void kernel_launch(void* const* d_in, const int* in_sizes, int n_in,
                              void* d_out, int out_size, void* d_ws, size_t ws_size,
                              hipStream_t stream) {
    const int*   inputs = (const int*)d_in[0];     // [32, 5000] int32
    const float* weight = (const float*)d_in[1];   // [32000, 512] fp32
    float*       out    = (float*)d_out;           // [32, 5000, 512] fp32

    const int total_threads = EMB_S * EMB_DV;      // 640,000
    const int block = 256;
    const int grid = (total_threads + block - 1) / block;  // 2500

    ComputeEmbeddings_50440095924269_kernel<<<grid, block, 0, stream>>>(
        inputs, weight, out);
}

// Round 3
// 98.845 us; speedup vs baseline: 1.0118x; 1.0118x over previous
//
#include <hip/hip_runtime.h>
#include <hip/hip_bf16.h>

// ComputeEmbeddings: out[b,s,d] = embed_weight[inputs[b,s], d] + PE[s,d]
//   B=32, S=5000, D=512, VOCAB=32000, fp32.
//
// R2 -> R3: fix compile error — __builtin_nontemporal_store needs a native
// clang vector type, not HIP's float4 class. Use ext_vector_type(4).
//
// Theory (from R1 counters): 328 MB output write stream sweeps the 256 MB
// L3 and evicts the 65.5 MB weight table -> random gathers re-fetch ~328 MB
// from HBM (dur matched ~660 MB total @ 6.6 TB/s). Nontemporal stores keep
// the write stream out of cache so the weight table stays L3-resident.

#define EMB_B 32
#define EMB_S 5000
#define EMB_D 512
#define EMB_DV (EMB_D / 4)   // 128 float4 per row

typedef float f32x4 __attribute__((ext_vector_type(4)));

__global__ __launch_bounds__(256) void ComputeEmbeddings_50440095924269_kernel(
    const int* __restrict__ inputs,      // [B, S]
    const float* __restrict__ weight,    // [VOCAB, D]
    float* __restrict__ out)             // [B, S, D]
{
    const int tid = blockIdx.x * blockDim.x + threadIdx.x;  // 0 .. S*EMB_DV-1
    const int dvec = tid & (EMB_DV - 1);     // 0..127  (d4 = dvec*4)
    const int s    = tid >> 7;               // 0..4999
    if (s >= EMB_S) return;

    // --- preload all 32 tokens (wave-uniform broadcast loads, independent) ---
    int tokens[EMB_B];
    #pragma unroll
    for (int b = 0; b < EMB_B; ++b) tokens[b] = inputs[b * EMB_S + s];

    // --- positional encoding for dims d4 .. d4+3 (pairs i0, i0+1) ---
    const int d4 = dvec << 2;
    const float LOG2_10000 = 13.287712379549449f;  // log2(10000)
    const float i0 = (float)(d4 >> 1);
    // inv_freq(i) = 10000^(-2i/D) = exp2(-(2i/D) * log2(10000))
    const float f0 = exp2f(-(2.0f * i0 / (float)EMB_D) * LOG2_10000);
    const float f1 = exp2f(-(2.0f * (i0 + 1.0f) / (float)EMB_D) * LOG2_10000);
    const float a0 = (float)s * f0;
    const float a1 = (float)s * f1;
    f32x4 pe;
    pe.x = sinf(a0); pe.y = cosf(a0);
    pe.z = sinf(a1); pe.w = cosf(a1);

    const f32x4* __restrict__ w4 = reinterpret_cast<const f32x4*>(weight);
    f32x4* __restrict__ o4 = reinterpret_cast<f32x4*>(out);
    const int row_off = s * EMB_DV + dvec;

    #pragma unroll 8
    for (int b = 0; b < EMB_B; ++b) {
        const f32x4 e = w4[(size_t)tokens[b] * EMB_DV + dvec];
        const f32x4 r = e + pe;
        __builtin_nontemporal_store(r, &o4[(size_t)b * (EMB_S * EMB_DV) + row_off]);
    }
}

extern "C" void kernel_launch(void* const* d_in, const int* in_sizes, int n_in,
                              void* d_out, int out_size, void* d_ws, size_t ws_size,
                              hipStream_t stream) {
    const int*   inputs = (const int*)d_in[0];     // [32, 5000] int32
    const float* weight = (const float*)d_in[1];   // [32000, 512] fp32
    float*       out    = (float*)d_out;           // [32, 5000, 512] fp32

    const int total_threads = EMB_S * EMB_DV;      // 640,000
    const int block = 256;
    const int grid = (total_threads + block - 1) / block;  // 2500

    ComputeEmbeddings_50440095924269_kernel<<<grid, block, 0, stream>>>(
        inputs, weight, out);
}